// Round 1
// baseline (1090.395 us; speedup 1.0000x reference)
//
#include <hip/hip_runtime.h>

// PhaMPN: message-passing network.
//   binput = fedges @ W_i ; message = sigmoid(binput)
//   5x: message = sigmoid(binput + (sum_8 message[egraph]) @ W_h)
//   nei = sum_8 message[agraph]; hidden = sigmoid([features|nei] @ W_o + b_o)
//   out = segment-mean(hidden) per scope row (B=500, len=100)

constexpr int Nn   = 50000;
constexpr int Ee   = 150000;
constexpr int NBn  = 8;
constexpr int Hh   = 128;
constexpr int FFn  = 40;
constexpr int KIN  = FFn + 1;    // 41
constexpr int KOUT = FFn + Hh;   // 168
constexpr int Bm   = 500;
constexpr int ITERS = 5;         // DEPTH - 1

__device__ __forceinline__ float sigmoidf_(float x) {
    return 1.0f / (1.0f + __expf(-x));
}

// ---------------------------------------------------------------------------
// Kernel 1: binput = fedges @ W_i ; msg = sigmoid(binput).  32 rows / block.
// ---------------------------------------------------------------------------
__global__ __launch_bounds__(256) void k_binput(
    const float* __restrict__ fedges, const float* __restrict__ W_i,
    float* __restrict__ binput, float* __restrict__ msg)
{
    __shared__ float sW[KIN][Hh];   // 41*128*4 = 21 KB
    __shared__ float sF[32][KIN];   // 32*41*4  = 5.25 KB
    const int t = threadIdx.x;
    const int row0 = blockIdx.x * 32;

    for (int i = t; i < KIN * Hh; i += 256) sW[i / Hh][i % Hh] = W_i[i];
    const int nrows = min(32, Ee - row0);
    for (int i = t; i < nrows * KIN; i += 256)
        sF[i / KIN][i % KIN] = fedges[(size_t)row0 * KIN + i];
    __syncthreads();

    const int tr = t >> 5, tc = t & 31;   // 8 row-groups x 32 col-groups
    float acc[4][4] = {};
    for (int k = 0; k < KIN; ++k) {
        float4 w = *(const float4*)&sW[k][tc * 4];
        #pragma unroll
        for (int rr = 0; rr < 4; ++rr) {
            float a = sF[tr * 4 + rr][k];
            acc[rr][0] = fmaf(a, w.x, acc[rr][0]);
            acc[rr][1] = fmaf(a, w.y, acc[rr][1]);
            acc[rr][2] = fmaf(a, w.z, acc[rr][2]);
            acc[rr][3] = fmaf(a, w.w, acc[rr][3]);
        }
    }
    #pragma unroll
    for (int rr = 0; rr < 4; ++rr) {
        int row = row0 + tr * 4 + rr;
        if (row < Ee) {
            size_t o = (size_t)row * Hh + tc * 4;
            float4 b = make_float4(acc[rr][0], acc[rr][1], acc[rr][2], acc[rr][3]);
            *(float4*)&binput[o] = b;
            float4 m = make_float4(sigmoidf_(b.x), sigmoidf_(b.y),
                                   sigmoidf_(b.z), sigmoidf_(b.w));
            *(float4*)&msg[o] = m;
        }
    }
}

// ---------------------------------------------------------------------------
// Kernel 2: msg_out = sigmoid(binput + (sum_8 msg_in[egraph]) @ W_h)
// 32 rows / block; W_h (64 KB) + nei tile (16 KB) in LDS.
// ---------------------------------------------------------------------------
__global__ __launch_bounds__(256) void k_iter(
    const float* __restrict__ msg_in, const int* __restrict__ egraph,
    const float* __restrict__ W_h, const float* __restrict__ binput,
    float* __restrict__ msg_out)
{
    __shared__ float sW[Hh][Hh];   // 64 KB
    __shared__ float sN[32][Hh];   // 16 KB
    const int t = threadIdx.x;
    const int row0 = blockIdx.x * 32;

    for (int i = t; i < (Hh * Hh) / 4; i += 256)
        ((float4*)sW)[i] = ((const float4*)W_h)[i];

    const int k4 = t & 31;      // which float4 of the 128-wide row
    const int rl = t >> 5;      // 0..7
    #pragma unroll
    for (int p = 0; p < 4; ++p) {
        int r = p * 8 + rl;
        int row = row0 + r;
        float4 s = make_float4(0.f, 0.f, 0.f, 0.f);
        if (row < Ee) {
            const int* eg = &egraph[(size_t)row * NBn];
            #pragma unroll
            for (int j = 0; j < NBn; ++j) {
                int idx = eg[j];
                float4 v = *(const float4*)&msg_in[(size_t)idx * Hh + k4 * 4];
                s.x += v.x; s.y += v.y; s.z += v.z; s.w += v.w;
            }
        }
        *(float4*)&sN[r][k4 * 4] = s;
    }
    __syncthreads();

    const int tr = t >> 5, tc = t & 31;
    float acc[4][4] = {};
    #pragma unroll 4
    for (int kk = 0; kk < Hh; kk += 4) {
        float4 w0 = *(const float4*)&sW[kk + 0][tc * 4];
        float4 w1 = *(const float4*)&sW[kk + 1][tc * 4];
        float4 w2 = *(const float4*)&sW[kk + 2][tc * 4];
        float4 w3 = *(const float4*)&sW[kk + 3][tc * 4];
        #pragma unroll
        for (int rr = 0; rr < 4; ++rr) {
            float4 a = *(const float4*)&sN[tr * 4 + rr][kk];
            acc[rr][0] = fmaf(a.x, w0.x, fmaf(a.y, w1.x, fmaf(a.z, w2.x, fmaf(a.w, w3.x, acc[rr][0]))));
            acc[rr][1] = fmaf(a.x, w0.y, fmaf(a.y, w1.y, fmaf(a.z, w2.y, fmaf(a.w, w3.y, acc[rr][1]))));
            acc[rr][2] = fmaf(a.x, w0.z, fmaf(a.y, w1.z, fmaf(a.z, w2.z, fmaf(a.w, w3.z, acc[rr][2]))));
            acc[rr][3] = fmaf(a.x, w0.w, fmaf(a.y, w1.w, fmaf(a.z, w2.w, fmaf(a.w, w3.w, acc[rr][3]))));
        }
    }

    #pragma unroll
    for (int rr = 0; rr < 4; ++rr) {
        int row = row0 + tr * 4 + rr;
        if (row < Ee) {
            size_t o = (size_t)row * Hh + tc * 4;
            float4 b = *(const float4*)&binput[o];
            float4 m = make_float4(sigmoidf_(acc[rr][0] + b.x),
                                   sigmoidf_(acc[rr][1] + b.y),
                                   sigmoidf_(acc[rr][2] + b.z),
                                   sigmoidf_(acc[rr][3] + b.w));
            *(float4*)&msg_out[o] = m;
        }
    }
}

// ---------------------------------------------------------------------------
// Kernel 3: hidden = sigmoid([features | sum_8 msg[agraph]] @ W_o + b_o)
// 32 rows / block; W_o (86 KB) + ain tile (21.5 KB) + b_o in LDS.
// ---------------------------------------------------------------------------
__global__ __launch_bounds__(256) void k_final(
    const float* __restrict__ msg_in, const int* __restrict__ agraph,
    const float* __restrict__ features, const float* __restrict__ W_o,
    const float* __restrict__ b_o, float* __restrict__ hidden)
{
    __shared__ float sW[KOUT][Hh];   // 168*128*4 = 84 KB
    __shared__ float sA[32][KOUT];   // 32*168*4  = 21 KB
    __shared__ float sB[Hh];
    const int t = threadIdx.x;
    const int row0 = blockIdx.x * 32;

    for (int i = t; i < (KOUT * Hh) / 4; i += 256)
        ((float4*)sW)[i] = ((const float4*)W_o)[i];
    if (t < Hh / 4) ((float4*)sB)[t] = ((const float4*)b_o)[t];

    const int nrows = min(32, Nn - row0);
    for (int i = t; i < nrows * FFn; i += 256)
        sA[i / FFn][i % FFn] = features[(size_t)row0 * FFn + i];

    const int k4 = t & 31;
    const int rl = t >> 5;
    #pragma unroll
    for (int p = 0; p < 4; ++p) {
        int r = p * 8 + rl;
        int row = row0 + r;
        float4 s = make_float4(0.f, 0.f, 0.f, 0.f);
        if (row < Nn) {
            const int* ag = &agraph[(size_t)row * NBn];
            #pragma unroll
            for (int j = 0; j < NBn; ++j) {
                int idx = ag[j];
                float4 v = *(const float4*)&msg_in[(size_t)idx * Hh + k4 * 4];
                s.x += v.x; s.y += v.y; s.z += v.z; s.w += v.w;
            }
        }
        *(float4*)&sA[r][FFn + k4 * 4] = s;
    }
    __syncthreads();

    const int tr = t >> 5, tc = t & 31;
    float acc[4][4] = {};
    #pragma unroll 4
    for (int kk = 0; kk < KOUT; kk += 4) {
        float4 w0 = *(const float4*)&sW[kk + 0][tc * 4];
        float4 w1 = *(const float4*)&sW[kk + 1][tc * 4];
        float4 w2 = *(const float4*)&sW[kk + 2][tc * 4];
        float4 w3 = *(const float4*)&sW[kk + 3][tc * 4];
        #pragma unroll
        for (int rr = 0; rr < 4; ++rr) {
            float4 a = *(const float4*)&sA[tr * 4 + rr][kk];
            acc[rr][0] = fmaf(a.x, w0.x, fmaf(a.y, w1.x, fmaf(a.z, w2.x, fmaf(a.w, w3.x, acc[rr][0]))));
            acc[rr][1] = fmaf(a.x, w0.y, fmaf(a.y, w1.y, fmaf(a.z, w2.y, fmaf(a.w, w3.y, acc[rr][1]))));
            acc[rr][2] = fmaf(a.x, w0.z, fmaf(a.y, w1.z, fmaf(a.z, w2.z, fmaf(a.w, w3.z, acc[rr][2]))));
            acc[rr][3] = fmaf(a.x, w0.w, fmaf(a.y, w1.w, fmaf(a.z, w2.w, fmaf(a.w, w3.w, acc[rr][3]))));
        }
    }

    #pragma unroll
    for (int rr = 0; rr < 4; ++rr) {
        int row = row0 + tr * 4 + rr;
        if (row < Nn) {
            size_t o = (size_t)row * Hh + tc * 4;
            float4 m = make_float4(sigmoidf_(acc[rr][0] + sB[tc * 4 + 0]),
                                   sigmoidf_(acc[rr][1] + sB[tc * 4 + 1]),
                                   sigmoidf_(acc[rr][2] + sB[tc * 4 + 2]),
                                   sigmoidf_(acc[rr][3] + sB[tc * 4 + 3]));
            *(float4*)&hidden[o] = m;
        }
    }
}

// ---------------------------------------------------------------------------
// Kernel 4: segment mean.  One block (128 threads) per molecule.
// scope[b] = (start, len); segments are consecutive row ranges.
// ---------------------------------------------------------------------------
__global__ __launch_bounds__(128) void k_pool(
    const float* __restrict__ hidden, const int* __restrict__ scope,
    float* __restrict__ out)
{
    const int b = blockIdx.x;
    const int t = threadIdx.x;
    const int start = scope[b * 2 + 0];
    const int len   = scope[b * 2 + 1];
    float acc = 0.f;
    for (int i = 0; i < len; ++i)
        acc += hidden[(size_t)(start + i) * Hh + t];
    out[(size_t)b * Hh + t] = acc / (float)len;
}

// ---------------------------------------------------------------------------
extern "C" void kernel_launch(void* const* d_in, const int* in_sizes, int n_in,
                              void* d_out, int out_size, void* d_ws, size_t ws_size,
                              hipStream_t stream)
{
    const float* features = (const float*)d_in[0];
    const float* fedges   = (const float*)d_in[1];
    const int*   agraph   = (const int*)d_in[2];
    const int*   egraph   = (const int*)d_in[3];
    const int*   scope    = (const int*)d_in[4];
    const float* W_i      = (const float*)d_in[5];
    const float* W_h      = (const float*)d_in[6];
    const float* W_o      = (const float*)d_in[7];
    const float* b_o      = (const float*)d_in[8];
    float* out = (float*)d_out;

    // Workspace layout (floats): binput[E*H] | msg0[E*H] | msg1[E*H]
    float* binput = (float*)d_ws;
    float* msg0   = binput + (size_t)Ee * Hh;
    float* msg1   = msg0 + (size_t)Ee * Hh;

    const int eblocks = (Ee + 31) / 32;
    k_binput<<<eblocks, 256, 0, stream>>>(fedges, W_i, binput, msg0);

    float* src = msg0;
    float* dst = msg1;
    for (int d = 0; d < ITERS; ++d) {
        k_iter<<<eblocks, 256, 0, stream>>>(src, egraph, W_h, binput, dst);
        float* tmp = src; src = dst; dst = tmp;
    }
    // final message lives in `src`; the other buffer is free for hidden.
    float* hidden = dst;

    const int nblocks = (Nn + 31) / 32;
    k_final<<<nblocks, 256, 0, stream>>>(src, agraph, features, W_o, b_o, hidden);

    k_pool<<<Bm, 128, 0, stream>>>(hidden, scope, out);
}

// Round 2
// 725.287 us; speedup vs baseline: 1.5034x; 1.5034x over previous
//
#include <hip/hip_runtime.h>

// PhaMPN: message-passing network, bf16-message + MFMA version.
//   binput = fedges @ W_i (f32); msg = bf16(sigmoid(binput))
//   5x: msg = bf16(sigmoid(binput + (sum_8 msg[egraph]) @ W_h))   [MFMA bf16, f32 accum]
//   nei = sum_8 msg[agraph]; hidden = sigmoid([features|nei] @ W_o + b_o)  (f32)
//   out = segment-mean(hidden) per scope row (B=500, len=100)

typedef __attribute__((ext_vector_type(4))) float f32x4;
typedef __attribute__((ext_vector_type(8))) short s16x8;

constexpr int Nn   = 50000;
constexpr int Ee   = 150000;
constexpr int NBn  = 8;
constexpr int Hh   = 128;
constexpr int FFn  = 40;
constexpr int KIN  = FFn + 1;    // 41
constexpr int KOUT = FFn + Hh;   // 168
constexpr int Bm   = 500;
constexpr int ITERS = 5;         // DEPTH - 1
constexpr int KP   = 136;        // padded bf16 row stride (2-way LDS bank aliasing = free)

__device__ __forceinline__ float sigmoidf_(float x) {
    return 1.0f / (1.0f + __expf(-x));
}
// f32 -> bf16 round-to-nearest-even (values are finite, no NaN handling needed)
__device__ __forceinline__ unsigned short f2bf(float f) {
    unsigned u = __float_as_uint(f);
    u += 0x7fffu + ((u >> 16) & 1u);
    return (unsigned short)(u >> 16);
}
__device__ __forceinline__ float bflo(unsigned u) { return __uint_as_float(u << 16); }
__device__ __forceinline__ float bfhi(unsigned u) { return __uint_as_float(u & 0xffff0000u); }

// ---------------------------------------------------------------------------
// Prep: wt[n*KP + k] = bf16(W_h[k][n])  (fragment-ready transposed weights)
// ---------------------------------------------------------------------------
__global__ __launch_bounds__(256) void k_prep_wh(
    const float* __restrict__ W_h, unsigned short* __restrict__ wt)
{
    int i = blockIdx.x * 256 + threadIdx.x;   // i = n*128 + k
    if (i < Hh * Hh) {
        int n = i >> 7, k = i & 127;
        wt[n * KP + k] = f2bf(W_h[k * Hh + n]);
    }
}

// ---------------------------------------------------------------------------
// Kernel 1: binput = fedges @ W_i (f32) ; msg = bf16(sigmoid(binput)).
// 32 rows / block, f32 vector FMA (K=41, small).
// ---------------------------------------------------------------------------
__global__ __launch_bounds__(256) void k_binput(
    const float* __restrict__ fedges, const float* __restrict__ W_i,
    float* __restrict__ binput, unsigned short* __restrict__ msg)
{
    __shared__ float sW[KIN][Hh];   // 21 KB
    __shared__ float sF[32][KIN];   // 5.25 KB
    const int t = threadIdx.x;
    const int row0 = blockIdx.x * 32;

    for (int i = t; i < KIN * Hh; i += 256) sW[i / Hh][i % Hh] = W_i[i];
    const int nrows = min(32, Ee - row0);
    for (int i = t; i < nrows * KIN; i += 256)
        sF[i / KIN][i % KIN] = fedges[(size_t)row0 * KIN + i];
    __syncthreads();

    const int tr = t >> 5, tc = t & 31;
    float acc[4][4] = {};
    for (int k = 0; k < KIN; ++k) {
        float4 w = *(const float4*)&sW[k][tc * 4];
        #pragma unroll
        for (int rr = 0; rr < 4; ++rr) {
            float a = sF[tr * 4 + rr][k];
            acc[rr][0] = fmaf(a, w.x, acc[rr][0]);
            acc[rr][1] = fmaf(a, w.y, acc[rr][1]);
            acc[rr][2] = fmaf(a, w.z, acc[rr][2]);
            acc[rr][3] = fmaf(a, w.w, acc[rr][3]);
        }
    }
    #pragma unroll
    for (int rr = 0; rr < 4; ++rr) {
        int row = row0 + tr * 4 + rr;
        if (row < Ee) {
            size_t o = (size_t)row * Hh + tc * 4;
            float4 b = make_float4(acc[rr][0], acc[rr][1], acc[rr][2], acc[rr][3]);
            *(float4*)&binput[o] = b;
            uint2 mo;
            mo.x = (unsigned)f2bf(sigmoidf_(b.x)) | ((unsigned)f2bf(sigmoidf_(b.y)) << 16);
            mo.y = (unsigned)f2bf(sigmoidf_(b.z)) | ((unsigned)f2bf(sigmoidf_(b.w)) << 16);
            *(uint2*)&msg[o] = mo;
        }
    }
}

// ---------------------------------------------------------------------------
// Kernel 2 (MFMA): msg_out = bf16(sigmoid(binput + (sum_8 msg_in[egraph]) @ W_h))
// 128 rows / block, 4 waves. LDS: wt 34KB + nei 34KB + eg 4KB = 72KB -> 2 blk/CU.
// ---------------------------------------------------------------------------
__global__ __launch_bounds__(256, 2) void k_iter(
    const unsigned short* __restrict__ msg_in, const int* __restrict__ egraph,
    const unsigned short* __restrict__ wt, const float* __restrict__ binput,
    unsigned short* __restrict__ msg_out)
{
    __shared__ unsigned short sW[Hh * KP];   // 34816 B, layout [n][k] (transposed W_h)
    __shared__ unsigned short sN[Hh * KP];   // 34816 B, layout [row][k]
    __shared__ int sEG[128 * NBn];           // 4 KB
    const int t = threadIdx.x;
    const int row0 = blockIdx.x * 128;

    // stage fragment-ready weights (linear uint4 copy, includes padding)
    for (int i = t; i < (Hh * KP) / 8; i += 256)
        ((uint4*)sW)[i] = ((const uint4*)wt)[i];
    // stage edge indices (int4 = half a row of 8)
    {
        int r = row0 + (t >> 1);
        int4 v = make_int4(0, 0, 0, 0);
        if (r < Ee) v = ((const int4*)egraph)[r * 2 + (t & 1)];
        ((int4*)sEG)[t] = v;
    }
    __syncthreads();

    // gather: 4 passes x 32 rows; 8 threads/row, each thread 32B (16 bf16)
    {
        const int s = t & 7, rl = t >> 3;   // s: segment, rl: 0..31
        #pragma unroll
        for (int pass = 0; pass < 4; ++pass) {
            int r = pass * 32 + rl;
            int grow = row0 + r;
            float acc[16];
            #pragma unroll
            for (int i = 0; i < 16; ++i) acc[i] = 0.f;
            if (grow < Ee) {
                #pragma unroll
                for (int j = 0; j < NBn; ++j) {
                    int idx = sEG[r * NBn + j];
                    const uint4* p = (const uint4*)(msg_in + (size_t)idx * Hh + s * 16);
                    uint4 v0 = p[0], v1 = p[1];
                    acc[0] += bflo(v0.x); acc[1] += bfhi(v0.x);
                    acc[2] += bflo(v0.y); acc[3] += bfhi(v0.y);
                    acc[4] += bflo(v0.z); acc[5] += bfhi(v0.z);
                    acc[6] += bflo(v0.w); acc[7] += bfhi(v0.w);
                    acc[8]  += bflo(v1.x); acc[9]  += bfhi(v1.x);
                    acc[10] += bflo(v1.y); acc[11] += bfhi(v1.y);
                    acc[12] += bflo(v1.z); acc[13] += bfhi(v1.z);
                    acc[14] += bflo(v1.w); acc[15] += bfhi(v1.w);
                }
            }
            uint4 o0, o1;
            o0.x = (unsigned)f2bf(acc[0])  | ((unsigned)f2bf(acc[1])  << 16);
            o0.y = (unsigned)f2bf(acc[2])  | ((unsigned)f2bf(acc[3])  << 16);
            o0.z = (unsigned)f2bf(acc[4])  | ((unsigned)f2bf(acc[5])  << 16);
            o0.w = (unsigned)f2bf(acc[6])  | ((unsigned)f2bf(acc[7])  << 16);
            o1.x = (unsigned)f2bf(acc[8])  | ((unsigned)f2bf(acc[9])  << 16);
            o1.y = (unsigned)f2bf(acc[10]) | ((unsigned)f2bf(acc[11]) << 16);
            o1.z = (unsigned)f2bf(acc[12]) | ((unsigned)f2bf(acc[13]) << 16);
            o1.w = (unsigned)f2bf(acc[14]) | ((unsigned)f2bf(acc[15]) << 16);
            *(uint4*)&sN[r * KP + s * 16]     = o0;
            *(uint4*)&sN[r * KP + s * 16 + 8] = o1;
        }
    }
    __syncthreads();

    // MFMA: wave wid owns rows wid*32..wid*32+31, all 128 cols.
    const int lane = t & 63, wid = t >> 6;
    const int l15 = lane & 15, l4 = lane >> 4;
    f32x4 acc[2][8];
    #pragma unroll
    for (int a = 0; a < 2; ++a)
        #pragma unroll
        for (int b = 0; b < 8; ++b) acc[a][b] = (f32x4){0.f, 0.f, 0.f, 0.f};

    #pragma unroll
    for (int ks = 0; ks < 4; ++ks) {
        s16x8 a0 = *(const s16x8*)&sN[(wid * 32 +      l15) * KP + ks * 32 + l4 * 8];
        s16x8 a1 = *(const s16x8*)&sN[(wid * 32 + 16 + l15) * KP + ks * 32 + l4 * 8];
        #pragma unroll
        for (int c = 0; c < 8; ++c) {
            s16x8 b = *(const s16x8*)&sW[(c * 16 + l15) * KP + ks * 32 + l4 * 8];
            acc[0][c] = __builtin_amdgcn_mfma_f32_16x16x32_bf16(a0, b, acc[0][c], 0, 0, 0);
            acc[1][c] = __builtin_amdgcn_mfma_f32_16x16x32_bf16(a1, b, acc[1][c], 0, 0, 0);
        }
    }
    __syncthreads();   // all MFMA A-reads of sN done before overwrite

    // epilogue: += binput, sigmoid, bf16 -> sN (D layout: col=lane&15, row=4*(lane>>4)+j)
    #pragma unroll
    for (int rt = 0; rt < 2; ++rt) {
        #pragma unroll
        for (int c = 0; c < 8; ++c) {
            #pragma unroll
            for (int j = 0; j < 4; ++j) {
                int rl_ = wid * 32 + rt * 16 + l4 * 4 + j;
                int grow = row0 + rl_;
                int col = c * 16 + l15;
                float b = 0.f;
                if (grow < Ee) b = binput[(size_t)grow * Hh + col];
                sN[rl_ * KP + col] = f2bf(sigmoidf_(acc[rt][c][j] + b));
            }
        }
    }
    __syncthreads();

    // coalesced copy out (16B per thread per iter)
    for (int i = t; i < Hh * 16; i += 256) {
        int r = i >> 4, seg = i & 15;
        int grow = row0 + r;
        if (grow < Ee)
            *(uint4*)(msg_out + (size_t)grow * Hh + seg * 8) = *(const uint4*)&sN[r * KP + seg * 8];
    }
}

// ---------------------------------------------------------------------------
// Kernel 3: hidden = sigmoid([features | sum_8 msg[agraph]] @ W_o + b_o)  (f32)
// ---------------------------------------------------------------------------
__global__ __launch_bounds__(256) void k_final(
    const unsigned short* __restrict__ msg_in, const int* __restrict__ agraph,
    const float* __restrict__ features, const float* __restrict__ W_o,
    const float* __restrict__ b_o, float* __restrict__ hidden)
{
    __shared__ float sW[KOUT][Hh];   // 84 KB
    __shared__ float sA[32][KOUT];   // 21 KB
    __shared__ float sB[Hh];
    const int t = threadIdx.x;
    const int row0 = blockIdx.x * 32;

    for (int i = t; i < (KOUT * Hh) / 4; i += 256)
        ((float4*)sW)[i] = ((const float4*)W_o)[i];
    if (t < Hh / 4) ((float4*)sB)[t] = ((const float4*)b_o)[t];

    const int nrows = min(32, Nn - row0);
    for (int i = t; i < nrows * FFn; i += 256)
        sA[i / FFn][i % FFn] = features[(size_t)row0 * FFn + i];

    // gather: 16 threads/row, each 16B (8 bf16); 2 passes of 16 rows
    const int seg = t & 15, rl = t >> 4;
    #pragma unroll
    for (int p = 0; p < 2; ++p) {
        int r = p * 16 + rl;
        int row = row0 + r;
        float a[8];
        #pragma unroll
        for (int i = 0; i < 8; ++i) a[i] = 0.f;
        if (row < Nn) {
            const int* ag = &agraph[(size_t)row * NBn];
            #pragma unroll
            for (int j = 0; j < NBn; ++j) {
                int idx = ag[j];
                uint4 v = *(const uint4*)(msg_in + (size_t)idx * Hh + seg * 8);
                a[0] += bflo(v.x); a[1] += bfhi(v.x);
                a[2] += bflo(v.y); a[3] += bfhi(v.y);
                a[4] += bflo(v.z); a[5] += bfhi(v.z);
                a[6] += bflo(v.w); a[7] += bfhi(v.w);
            }
        }
        *(float4*)&sA[r][FFn + seg * 8]     = make_float4(a[0], a[1], a[2], a[3]);
        *(float4*)&sA[r][FFn + seg * 8 + 4] = make_float4(a[4], a[5], a[6], a[7]);
    }
    __syncthreads();

    const int tr = t >> 5, tc = t & 31;
    float acc[4][4] = {};
    #pragma unroll 4
    for (int kk = 0; kk < KOUT; kk += 4) {
        float4 w0 = *(const float4*)&sW[kk + 0][tc * 4];
        float4 w1 = *(const float4*)&sW[kk + 1][tc * 4];
        float4 w2 = *(const float4*)&sW[kk + 2][tc * 4];
        float4 w3 = *(const float4*)&sW[kk + 3][tc * 4];
        #pragma unroll
        for (int rr = 0; rr < 4; ++rr) {
            float4 a = *(const float4*)&sA[tr * 4 + rr][kk];
            acc[rr][0] = fmaf(a.x, w0.x, fmaf(a.y, w1.x, fmaf(a.z, w2.x, fmaf(a.w, w3.x, acc[rr][0]))));
            acc[rr][1] = fmaf(a.x, w0.y, fmaf(a.y, w1.y, fmaf(a.z, w2.y, fmaf(a.w, w3.y, acc[rr][1]))));
            acc[rr][2] = fmaf(a.x, w0.z, fmaf(a.y, w1.z, fmaf(a.z, w2.z, fmaf(a.w, w3.z, acc[rr][2]))));
            acc[rr][3] = fmaf(a.x, w0.w, fmaf(a.y, w1.w, fmaf(a.z, w2.w, fmaf(a.w, w3.w, acc[rr][3]))));
        }
    }

    #pragma unroll
    for (int rr = 0; rr < 4; ++rr) {
        int row = row0 + tr * 4 + rr;
        if (row < Nn) {
            size_t o = (size_t)row * Hh + tc * 4;
            float4 m = make_float4(sigmoidf_(acc[rr][0] + sB[tc * 4 + 0]),
                                   sigmoidf_(acc[rr][1] + sB[tc * 4 + 1]),
                                   sigmoidf_(acc[rr][2] + sB[tc * 4 + 2]),
                                   sigmoidf_(acc[rr][3] + sB[tc * 4 + 3]));
            *(float4*)&hidden[o] = m;
        }
    }
}

// ---------------------------------------------------------------------------
// Kernel 4: segment mean.  One block (128 threads) per molecule.
// ---------------------------------------------------------------------------
__global__ __launch_bounds__(128) void k_pool(
    const float* __restrict__ hidden, const int* __restrict__ scope,
    float* __restrict__ out)
{
    const int b = blockIdx.x;
    const int t = threadIdx.x;
    const int start = scope[b * 2 + 0];
    const int len   = scope[b * 2 + 1];
    float acc = 0.f;
    for (int i = 0; i < len; ++i)
        acc += hidden[(size_t)(start + i) * Hh + t];
    out[(size_t)b * Hh + t] = acc / (float)len;
}

// ---------------------------------------------------------------------------
extern "C" void kernel_launch(void* const* d_in, const int* in_sizes, int n_in,
                              void* d_out, int out_size, void* d_ws, size_t ws_size,
                              hipStream_t stream)
{
    const float* features = (const float*)d_in[0];
    const float* fedges   = (const float*)d_in[1];
    const int*   agraph   = (const int*)d_in[2];
    const int*   egraph   = (const int*)d_in[3];
    const int*   scope    = (const int*)d_in[4];
    const float* W_i      = (const float*)d_in[5];
    const float* W_h      = (const float*)d_in[6];
    const float* W_o      = (const float*)d_in[7];
    const float* b_o      = (const float*)d_in[8];
    float* out = (float*)d_out;

    // Workspace (bytes): binput f32[E*H] | msg0 bf16[E*H] | msg1 bf16[E*H] | wt bf16[H*KP]
    float* binput = (float*)d_ws;
    unsigned short* msg0 = (unsigned short*)(binput + (size_t)Ee * Hh);
    unsigned short* msg1 = msg0 + (size_t)Ee * Hh;
    unsigned short* wt   = msg1 + (size_t)Ee * Hh;

    k_prep_wh<<<(Hh * Hh + 255) / 256, 256, 0, stream>>>(W_h, wt);

    const int eblocks32 = (Ee + 31) / 32;
    k_binput<<<eblocks32, 256, 0, stream>>>(fedges, W_i, binput, msg0);

    unsigned short* src = msg0;
    unsigned short* dst = msg1;
    const int eblocks128 = (Ee + 127) / 128;
    for (int d = 0; d < ITERS; ++d) {
        k_iter<<<eblocks128, 256, 0, stream>>>(src, egraph, wt, binput, dst);
        unsigned short* tmp = src; src = dst; dst = tmp;
    }
    // final message in `src`; reuse `dst` region (38.4 MB) for hidden f32 (25.6 MB)
    float* hidden = (float*)dst;

    const int nblocks = (Nn + 31) / 32;
    k_final<<<nblocks, 256, 0, stream>>>(src, agraph, features, W_o, b_o, hidden);

    k_pool<<<Bm, 128, 0, stream>>>(hidden, scope, out);
}

// Round 3
// 468.702 us; speedup vs baseline: 2.3264x; 1.5474x over previous
//
#include <hip/hip_runtime.h>

// PhaMPN: message-passing network, bf16-message + MFMA pipeline.
//   binput = fedges @ W_i (MFMA bf16, stored f32); msg = bf16(sigmoid(binput))
//   5x: msg = bf16(sigmoid(binput + (sum_8 msg[egraph]) @ W_h))   [MFMA bf16]
//   nei = sum_8 msg[agraph]; hidden = bf16(sigmoid([feat|nei] @ W_o + b_o)) [MFMA]
//   out = segment-mean(hidden) per scope row (B=500, len=100), f32

typedef __attribute__((ext_vector_type(4))) float f32x4;
typedef __attribute__((ext_vector_type(8))) short s16x8;
typedef unsigned short u16;

constexpr int Nn   = 50000;
constexpr int Ee   = 150000;
constexpr int NBn  = 8;
constexpr int Hh   = 128;
constexpr int FFn  = 40;
constexpr int Bm   = 500;
constexpr int ITERS = 5;       // DEPTH - 1
constexpr int KP   = 136;      // W_h / nei-tile bf16 row stride (2-way bank = free)
constexpr int KI   = 72;       // W_i / fedges-tile stride, K padded 41->64
constexpr int KO   = 200;      // W_o / A-tile stride, K padded 168->192
constexpr int ACCW = 132;      // f32 acc LDS stride (2-way bank = free)

__device__ __forceinline__ float sigmoidf_(float x) {
    return 1.0f / (1.0f + __expf(-x));
}
// f32 -> bf16 round-to-nearest-even (finite values only)
__device__ __forceinline__ u16 f2bf(float f) {
    unsigned u = __float_as_uint(f);
    u += 0x7fffu + ((u >> 16) & 1u);
    return (u16)(u >> 16);
}
__device__ __forceinline__ float bflo(unsigned u) { return __uint_as_float(u << 16); }
__device__ __forceinline__ float bfhi(unsigned u) { return __uint_as_float(u & 0xffff0000u); }
__device__ __forceinline__ float bf1(u16 h) { return __uint_as_float(((unsigned)h) << 16); }
__device__ __forceinline__ unsigned pack2(float x, float y) {
    return (unsigned)f2bf(x) | ((unsigned)f2bf(y) << 16);
}
__device__ __forceinline__ void add8(float* a, uint4 v) {
    a[0] += bflo(v.x); a[1] += bfhi(v.x); a[2] += bflo(v.y); a[3] += bfhi(v.y);
    a[4] += bflo(v.z); a[5] += bfhi(v.z); a[6] += bflo(v.w); a[7] += bfhi(v.w);
}

// ---------------------------------------------------------------------------
// Prep 1: wt_h[n*KP+k] = bf16(W_h[k][n]) (k<128 else 0)
//         wt_i[n*KI+k] = bf16(W_i[k][n]) (k<41 else 0)
// ---------------------------------------------------------------------------
__global__ __launch_bounds__(256) void k_prep1(
    const float* __restrict__ W_h, const float* __restrict__ W_i,
    u16* __restrict__ wt_h, u16* __restrict__ wt_i)
{
    int i = blockIdx.x * 256 + threadIdx.x;
    if (i < Hh * KP) {
        int n = i / KP, k = i - n * KP;
        wt_h[i] = (k < Hh) ? f2bf(W_h[k * Hh + n]) : (u16)0;
    } else {
        int j = i - Hh * KP;
        if (j < Hh * KI) {
            int n = j / KI, k = j - n * KI;
            wt_i[j] = (k < 41) ? f2bf(W_i[k * Hh + n]) : (u16)0;
        }
    }
}

// ---------------------------------------------------------------------------
// Prep 2: wt_o[n*KO+k]: k<40 -> W_o[k][n]; 40..63 -> 0; 64..191 -> W_o[k-24][n]
// ---------------------------------------------------------------------------
__global__ __launch_bounds__(256) void k_prep2(
    const float* __restrict__ W_o, u16* __restrict__ wt_o)
{
    int i = blockIdx.x * 256 + threadIdx.x;
    if (i < Hh * KO) {
        int n = i / KO, k = i - n * KO;
        u16 v = 0;
        if (k < FFn)                 v = f2bf(W_o[k * Hh + n]);
        else if (k >= 64 && k < 192) v = f2bf(W_o[(k - 24) * Hh + n]);
        wt_o[i] = v;
    }
}

// ---------------------------------------------------------------------------
// Kernel 1 (MFMA): binput = fedges @ W_i (f32 out); msg = bf16(sigmoid(binput))
// 128 rows / block, 4 waves, K=64 (padded).
// ---------------------------------------------------------------------------
union BinSmem {
    struct { u16 Wi[Hh * KI]; u16 A[Hh * KI]; } s;   // 36864 B
    float acc[Hh][ACCW];                             // 67584 B
};

__global__ __launch_bounds__(256, 2) void k_binput(
    const float* __restrict__ fedges, const u16* __restrict__ wt_i,
    float* __restrict__ binput, u16* __restrict__ msg)
{
    __shared__ BinSmem u;
    const int t = threadIdx.x;
    const int row0 = blockIdx.x * 128;
    const int nvalid = min(128, Ee - row0);

    {
        uint4 z = make_uint4(0, 0, 0, 0);
        for (int i = t; i < Hh * KI / 8; i += 256) {
            ((uint4*)u.s.Wi)[i] = ((const uint4*)wt_i)[i];
            ((uint4*)u.s.A)[i] = z;
        }
    }
    __syncthreads();
    for (int i = t; i < nvalid * 41; i += 256) {
        int r = i / 41, k = i - r * 41;
        u.s.A[r * KI + k] = f2bf(fedges[(size_t)row0 * 41 + i]);
    }
    __syncthreads();

    const int lane = t & 63, wid = t >> 6, l15 = lane & 15, l4 = lane >> 4;
    f32x4 acc[2][8];
    #pragma unroll
    for (int a = 0; a < 2; ++a)
        #pragma unroll
        for (int b = 0; b < 8; ++b) acc[a][b] = (f32x4){0.f, 0.f, 0.f, 0.f};

    #pragma unroll
    for (int ks = 0; ks < 2; ++ks) {
        s16x8 a0 = *(const s16x8*)&u.s.A[(wid * 32 +      l15) * KI + ks * 32 + l4 * 8];
        s16x8 a1 = *(const s16x8*)&u.s.A[(wid * 32 + 16 + l15) * KI + ks * 32 + l4 * 8];
        #pragma unroll
        for (int c = 0; c < 8; ++c) {
            s16x8 b = *(const s16x8*)&u.s.Wi[(c * 16 + l15) * KI + ks * 32 + l4 * 8];
            acc[0][c] = __builtin_amdgcn_mfma_f32_16x16x32_bf16(a0, b, acc[0][c], 0, 0, 0);
            acc[1][c] = __builtin_amdgcn_mfma_f32_16x16x32_bf16(a1, b, acc[1][c], 0, 0, 0);
        }
    }
    __syncthreads();

    #pragma unroll
    for (int rt = 0; rt < 2; ++rt)
        #pragma unroll
        for (int c = 0; c < 8; ++c)
            #pragma unroll
            for (int j = 0; j < 4; ++j)
                u.acc[wid * 32 + rt * 16 + l4 * 4 + j][c * 16 + l15] = acc[rt][c][j];
    __syncthreads();

    for (int i = t; i < Hh * 16; i += 256) {
        int row = i >> 4, seg = i & 15, grow = row0 + row;
        if (grow < Ee) {
            float4 a0 = *(const float4*)&u.acc[row][seg * 8];
            float4 a1 = *(const float4*)&u.acc[row][seg * 8 + 4];
            size_t o = (size_t)grow * Hh + seg * 8;
            *(float4*)&binput[o]     = a0;
            *(float4*)&binput[o + 4] = a1;
            uint4 m;
            m.x = pack2(sigmoidf_(a0.x), sigmoidf_(a0.y));
            m.y = pack2(sigmoidf_(a0.z), sigmoidf_(a0.w));
            m.z = pack2(sigmoidf_(a1.x), sigmoidf_(a1.y));
            m.w = pack2(sigmoidf_(a1.z), sigmoidf_(a1.w));
            *(uint4*)&msg[o] = m;
        }
    }
}

// ---------------------------------------------------------------------------
// Kernel 2 (MFMA): msg_out = bf16(sigmoid(binput + (sum_8 msg_in[egraph]) @ W_h))
// 128 rows / block. LDS: union(W+N bf16 | acc f32) 68KB + eg 4KB -> 2 blk/CU.
// ---------------------------------------------------------------------------
union IterSmem {
    struct { u16 W[Hh * KP]; u16 N[Hh * KP]; } s;    // 69632 B
    float acc[Hh][ACCW];                             // 67584 B
};

__global__ __launch_bounds__(256, 2) void k_iter(
    const u16* __restrict__ msg_in, const int* __restrict__ egraph,
    const u16* __restrict__ wt_h, const float* __restrict__ binput,
    u16* __restrict__ msg_out)
{
    __shared__ IterSmem u;
    __shared__ int sEG[128 * NBn];
    const int t = threadIdx.x;
    const int row0 = blockIdx.x * 128;

    for (int i = t; i < Hh * KP / 8; i += 256)
        ((uint4*)u.s.W)[i] = ((const uint4*)wt_h)[i];
    {
        int r = row0 + (t >> 1);
        int4 v = make_int4(0, 0, 0, 0);
        if (r < Ee) v = ((const int4*)egraph)[r * 2 + (t & 1)];
        ((int4*)sEG)[t] = v;
    }
    __syncthreads();

    // gather: 16 lanes/row x 16B -> each quarter-wave reads a full 256B msg row
    {
        const int s = t & 15, rl = t >> 4;
        #pragma unroll 2
        for (int pass = 0; pass < 8; ++pass) {
            int r = pass * 16 + rl;
            int grow = row0 + r;
            float a[8] = {0.f, 0.f, 0.f, 0.f, 0.f, 0.f, 0.f, 0.f};
            if (grow < Ee) {
                #pragma unroll
                for (int j = 0; j < NBn; ++j) {
                    int idx = sEG[r * NBn + j];
                    uint4 v = *(const uint4*)(msg_in + (size_t)idx * Hh + s * 8);
                    add8(a, v);
                }
            }
            uint4 o;
            o.x = pack2(a[0], a[1]); o.y = pack2(a[2], a[3]);
            o.z = pack2(a[4], a[5]); o.w = pack2(a[6], a[7]);
            *(uint4*)&u.s.N[r * KP + s * 8] = o;
        }
    }
    __syncthreads();

    const int lane = t & 63, wid = t >> 6, l15 = lane & 15, l4 = lane >> 4;
    f32x4 acc[2][8];
    #pragma unroll
    for (int a = 0; a < 2; ++a)
        #pragma unroll
        for (int b = 0; b < 8; ++b) acc[a][b] = (f32x4){0.f, 0.f, 0.f, 0.f};

    #pragma unroll
    for (int ks = 0; ks < 4; ++ks) {
        s16x8 a0 = *(const s16x8*)&u.s.N[(wid * 32 +      l15) * KP + ks * 32 + l4 * 8];
        s16x8 a1 = *(const s16x8*)&u.s.N[(wid * 32 + 16 + l15) * KP + ks * 32 + l4 * 8];
        #pragma unroll
        for (int c = 0; c < 8; ++c) {
            s16x8 b = *(const s16x8*)&u.s.W[(c * 16 + l15) * KP + ks * 32 + l4 * 8];
            acc[0][c] = __builtin_amdgcn_mfma_f32_16x16x32_bf16(a0, b, acc[0][c], 0, 0, 0);
            acc[1][c] = __builtin_amdgcn_mfma_f32_16x16x32_bf16(a1, b, acc[1][c], 0, 0, 0);
        }
    }
    __syncthreads();

    #pragma unroll
    for (int rt = 0; rt < 2; ++rt)
        #pragma unroll
        for (int c = 0; c < 8; ++c)
            #pragma unroll
            for (int j = 0; j < 4; ++j)
                u.acc[wid * 32 + rt * 16 + l4 * 4 + j][c * 16 + l15] = acc[rt][c][j];
    __syncthreads();

    for (int i = t; i < Hh * 16; i += 256) {
        int row = i >> 4, seg = i & 15, grow = row0 + row;
        if (grow < Ee) {
            float4 a0 = *(const float4*)&u.acc[row][seg * 8];
            float4 a1 = *(const float4*)&u.acc[row][seg * 8 + 4];
            size_t o = (size_t)grow * Hh + seg * 8;
            float4 b0 = *(const float4*)&binput[o];
            float4 b1 = *(const float4*)&binput[o + 4];
            uint4 m;
            m.x = pack2(sigmoidf_(a0.x + b0.x), sigmoidf_(a0.y + b0.y));
            m.y = pack2(sigmoidf_(a0.z + b0.z), sigmoidf_(a0.w + b0.w));
            m.z = pack2(sigmoidf_(a1.x + b1.x), sigmoidf_(a1.y + b1.y));
            m.w = pack2(sigmoidf_(a1.z + b1.z), sigmoidf_(a1.w + b1.w));
            *(uint4*)&msg_out[o] = m;
        }
    }
}

// ---------------------------------------------------------------------------
// Kernel 3 (MFMA): hidden = bf16(sigmoid([feat|0pad|nei] @ W_o' + b_o)), K=192
// 64 rows / block, 4 waves. LDS 79360 B -> 2 blk/CU.
// ---------------------------------------------------------------------------
union WoSmem {
    u16 Wo[Hh * KO];        // 51200 B
    float acc[64][ACCW];    // 33792 B
};

__global__ __launch_bounds__(256, 2) void k_final(
    const u16* __restrict__ msg_in, const int* __restrict__ agraph,
    const float* __restrict__ features, const u16* __restrict__ wt_o,
    const float* __restrict__ b_o, u16* __restrict__ hidden)
{
    __shared__ WoSmem uw;
    __shared__ u16 sA[64 * KO];     // 25600 B
    __shared__ int sAG[64 * NBn];   // 2048 B
    __shared__ float sBias[Hh];     // 512 B
    const int t = threadIdx.x;
    const int row0 = blockIdx.x * 64;
    const int nvalid = min(64, Nn - row0);

    for (int i = t; i < Hh * KO / 8; i += 256)
        ((uint4*)uw.Wo)[i] = ((const uint4*)wt_o)[i];
    {
        uint4 z = make_uint4(0, 0, 0, 0);
        for (int i = t; i < 64 * KO / 8; i += 256) ((uint4*)sA)[i] = z;
    }
    if (t < 128) {
        int r = row0 + (t >> 1);
        int4 v = make_int4(0, 0, 0, 0);
        if (r < Nn) v = ((const int4*)agraph)[r * 2 + (t & 1)];
        ((int4*)sAG)[t] = v;
    }
    if (t < Hh / 4) ((float4*)sBias)[t] = ((const float4*)b_o)[t];
    __syncthreads();

    for (int i = t; i < nvalid * FFn; i += 256) {
        int r = i / FFn, k = i - r * FFn;
        sA[r * KO + k] = f2bf(features[(size_t)row0 * FFn + i]);
    }
    {
        const int s = t & 15, rl = t >> 4;
        #pragma unroll 2
        for (int pass = 0; pass < 4; ++pass) {
            int r = pass * 16 + rl;
            int grow = row0 + r;
            float a[8] = {0.f, 0.f, 0.f, 0.f, 0.f, 0.f, 0.f, 0.f};
            if (grow < Nn) {
                #pragma unroll
                for (int j = 0; j < NBn; ++j) {
                    int idx = sAG[r * NBn + j];
                    uint4 v = *(const uint4*)(msg_in + (size_t)idx * Hh + s * 8);
                    add8(a, v);
                }
            }
            uint4 o;
            o.x = pack2(a[0], a[1]); o.y = pack2(a[2], a[3]);
            o.z = pack2(a[4], a[5]); o.w = pack2(a[6], a[7]);
            *(uint4*)&sA[r * KO + 64 + s * 8] = o;
        }
    }
    __syncthreads();

    const int lane = t & 63, wid = t >> 6, l15 = lane & 15, l4 = lane >> 4;
    f32x4 acc[8];
    #pragma unroll
    for (int b = 0; b < 8; ++b) acc[b] = (f32x4){0.f, 0.f, 0.f, 0.f};

    #pragma unroll
    for (int ks = 0; ks < 6; ++ks) {
        s16x8 a = *(const s16x8*)&sA[(wid * 16 + l15) * KO + ks * 32 + l4 * 8];
        #pragma unroll
        for (int c = 0; c < 8; ++c) {
            s16x8 b = *(const s16x8*)&uw.Wo[(c * 16 + l15) * KO + ks * 32 + l4 * 8];
            acc[c] = __builtin_amdgcn_mfma_f32_16x16x32_bf16(a, b, acc[c], 0, 0, 0);
        }
    }
    __syncthreads();

    #pragma unroll
    for (int c = 0; c < 8; ++c)
        #pragma unroll
        for (int j = 0; j < 4; ++j)
            uw.acc[wid * 16 + l4 * 4 + j][c * 16 + l15] = acc[c][j];
    __syncthreads();

    for (int i = t; i < 64 * 16; i += 256) {
        int row = i >> 4, seg = i & 15, grow = row0 + row;
        if (grow < Nn) {
            float4 a0 = *(const float4*)&uw.acc[row][seg * 8];
            float4 a1 = *(const float4*)&uw.acc[row][seg * 8 + 4];
            const float* bb = &sBias[seg * 8];
            uint4 m;
            m.x = pack2(sigmoidf_(a0.x + bb[0]), sigmoidf_(a0.y + bb[1]));
            m.y = pack2(sigmoidf_(a0.z + bb[2]), sigmoidf_(a0.w + bb[3]));
            m.z = pack2(sigmoidf_(a1.x + bb[4]), sigmoidf_(a1.y + bb[5]));
            m.w = pack2(sigmoidf_(a1.z + bb[6]), sigmoidf_(a1.w + bb[7]));
            *(uint4*)&hidden[(size_t)grow * Hh + seg * 8] = m;
        }
    }
}

// ---------------------------------------------------------------------------
// Kernel 4: segment mean over bf16 hidden. One block (128 threads) / molecule.
// ---------------------------------------------------------------------------
__global__ __launch_bounds__(128) void k_pool(
    const u16* __restrict__ hidden, const int* __restrict__ scope,
    float* __restrict__ out)
{
    const int b = blockIdx.x;
    const int t = threadIdx.x;
    const int start = scope[b * 2 + 0];
    const int len   = scope[b * 2 + 1];
    float acc = 0.f;
    for (int i = 0; i < len; ++i)
        acc += bf1(hidden[(size_t)(start + i) * Hh + t]);
    out[(size_t)b * Hh + t] = acc / (float)len;
}

// ---------------------------------------------------------------------------
extern "C" void kernel_launch(void* const* d_in, const int* in_sizes, int n_in,
                              void* d_out, int out_size, void* d_ws, size_t ws_size,
                              hipStream_t stream)
{
    const float* features = (const float*)d_in[0];
    const float* fedges   = (const float*)d_in[1];
    const int*   agraph   = (const int*)d_in[2];
    const int*   egraph   = (const int*)d_in[3];
    const int*   scope    = (const int*)d_in[4];
    const float* W_i      = (const float*)d_in[5];
    const float* W_h      = (const float*)d_in[6];
    const float* W_o      = (const float*)d_in[7];
    const float* b_o      = (const float*)d_in[8];
    float* out = (float*)d_out;

    // Workspace: binput f32[E*128] | msg0 bf16[E*128] | msg1 bf16[E*128] | wt_h
    // wt_i parks in msg1 (dead until iter0 writes it); wt_o parks in binput
    // (dead after iter5) and is prepped just before k_final.
    float* binput = (float*)d_ws;
    u16* msg0 = (u16*)(binput + (size_t)Ee * Hh);
    u16* msg1 = msg0 + (size_t)Ee * Hh;
    u16* wt_h = msg1 + (size_t)Ee * Hh;
    u16* wt_i = msg1;            // 18432 B, consumed by k_binput only
    u16* wt_o = (u16*)binput;    // 51200 B, consumed by k_final only

    k_prep1<<<(Hh * KP + Hh * KI) / 256, 256, 0, stream>>>(W_h, W_i, wt_h, wt_i);

    const int eblocks = (Ee + 127) / 128;
    k_binput<<<eblocks, 256, 0, stream>>>(fedges, wt_i, binput, msg0);

    u16* src = msg0;
    u16* dst = msg1;
    for (int d = 0; d < ITERS; ++d) {
        k_iter<<<eblocks, 256, 0, stream>>>(src, egraph, wt_h, binput, dst);
        u16* tmp = src; src = dst; dst = tmp;
    }
    // final message in `src` (= msg1); binput now dead -> prep wt_o there.
    k_prep2<<<(Hh * KO) / 256, 256, 0, stream>>>(W_o, wt_o);

    u16* hidden = dst;   // = msg0 region, 38.4 MB >= 12.8 MB needed
    const int nblocks = (Nn + 63) / 64;
    k_final<<<nblocks, 256, 0, stream>>>(src, agraph, features, wt_o, b_o, hidden);

    k_pool<<<Bm, 128, 0, stream>>>(hidden, scope, out);
}

// Round 4
// 459.676 us; speedup vs baseline: 2.3721x; 1.0196x over previous
//
#include <hip/hip_runtime.h>

// PhaMPN: message-passing network, bf16-message + MFMA pipeline, v4.
//   binput = fedges @ W_i (MFMA, stored bf16); msg = bf16(sigmoid(binput))
//   5x: msg = bf16(sigmoid(binput + (sum_8 msg[egraph]) @ W_h))   [MFMA bf16]
//   nei = sum_8 msg[agraph]; hidden = bf16(sigmoid([feat|nei] @ W_o + b_o)) [MFMA]
//   out = segment-mean(hidden) per scope row (B=500, len=100), f32
// v4: k_iter/k_binput at 512 threads (8 waves, same 128-row tile, same LDS)
//     -> 16 waves/CU instead of 8; binput stored bf16 (halves its HBM traffic).

typedef __attribute__((ext_vector_type(4))) float f32x4;
typedef __attribute__((ext_vector_type(8))) short s16x8;
typedef unsigned short u16;

constexpr int Nn   = 50000;
constexpr int Ee   = 150000;
constexpr int NBn  = 8;
constexpr int Hh   = 128;
constexpr int FFn  = 40;
constexpr int Bm   = 500;
constexpr int ITERS = 5;       // DEPTH - 1
constexpr int KP   = 136;      // W_h / nei-tile bf16 row stride
constexpr int KI   = 72;       // W_i / fedges-tile stride, K padded 41->64
constexpr int KO   = 200;      // W_o / A-tile stride, K padded 168->192
constexpr int ACCW = 132;      // f32 acc LDS stride

__device__ __forceinline__ float sigmoidf_(float x) {
    return 1.0f / (1.0f + __expf(-x));
}
// f32 -> bf16 round-to-nearest-even (finite values only)
__device__ __forceinline__ u16 f2bf(float f) {
    unsigned u = __float_as_uint(f);
    u += 0x7fffu + ((u >> 16) & 1u);
    return (u16)(u >> 16);
}
__device__ __forceinline__ float bflo(unsigned u) { return __uint_as_float(u << 16); }
__device__ __forceinline__ float bfhi(unsigned u) { return __uint_as_float(u & 0xffff0000u); }
__device__ __forceinline__ float bf1(u16 h) { return __uint_as_float(((unsigned)h) << 16); }
__device__ __forceinline__ unsigned pack2(float x, float y) {
    return (unsigned)f2bf(x) | ((unsigned)f2bf(y) << 16);
}
__device__ __forceinline__ void add8(float* a, uint4 v) {
    a[0] += bflo(v.x); a[1] += bfhi(v.x); a[2] += bflo(v.y); a[3] += bfhi(v.y);
    a[4] += bflo(v.z); a[5] += bfhi(v.z); a[6] += bflo(v.w); a[7] += bfhi(v.w);
}

// ---------------------------------------------------------------------------
// Prep 1: wt_h[n*KP+k] = bf16(W_h[k][n]); wt_i[n*KI+k] = bf16(W_i[k][n]) (0-pad)
// ---------------------------------------------------------------------------
__global__ __launch_bounds__(256) void k_prep1(
    const float* __restrict__ W_h, const float* __restrict__ W_i,
    u16* __restrict__ wt_h, u16* __restrict__ wt_i)
{
    int i = blockIdx.x * 256 + threadIdx.x;
    if (i < Hh * KP) {
        int n = i / KP, k = i - n * KP;
        wt_h[i] = (k < Hh) ? f2bf(W_h[k * Hh + n]) : (u16)0;
    } else {
        int j = i - Hh * KP;
        if (j < Hh * KI) {
            int n = j / KI, k = j - n * KI;
            wt_i[j] = (k < 41) ? f2bf(W_i[k * Hh + n]) : (u16)0;
        }
    }
}

// ---------------------------------------------------------------------------
// Prep 2: wt_o[n*KO+k]: k<40 -> W_o[k][n]; 40..63 -> 0; 64..191 -> W_o[k-24][n]
// ---------------------------------------------------------------------------
__global__ __launch_bounds__(256) void k_prep2(
    const float* __restrict__ W_o, u16* __restrict__ wt_o)
{
    int i = blockIdx.x * 256 + threadIdx.x;
    if (i < Hh * KO) {
        int n = i / KO, k = i - n * KO;
        u16 v = 0;
        if (k < FFn)                 v = f2bf(W_o[k * Hh + n]);
        else if (k >= 64 && k < 192) v = f2bf(W_o[(k - 24) * Hh + n]);
        wt_o[i] = v;
    }
}

// ---------------------------------------------------------------------------
// Kernel 1 (MFMA, 512 thr): binput_bf = bf16(fedges @ W_i); msg = bf16(sigmoid)
// 128 rows / block, 8 waves, K=64 (padded). LDS 66KB -> 2 blk/CU, 16 waves/CU.
// ---------------------------------------------------------------------------
union BinSmem {
    struct { u16 Wi[Hh * KI]; u16 A[Hh * KI]; } s;   // 36864 B
    float acc[Hh][ACCW];                             // 67584 B
};

__global__ __launch_bounds__(512, 4) void k_binput(
    const float* __restrict__ fedges, const u16* __restrict__ wt_i,
    u16* __restrict__ binput_bf, u16* __restrict__ msg)
{
    __shared__ BinSmem u;
    const int t = threadIdx.x;
    const int row0 = blockIdx.x * 128;
    const int nvalid = min(128, Ee - row0);

    {
        uint4 z = make_uint4(0, 0, 0, 0);
        for (int i = t; i < Hh * KI / 8; i += 512) {
            ((uint4*)u.s.Wi)[i] = ((const uint4*)wt_i)[i];
            ((uint4*)u.s.A)[i] = z;
        }
    }
    __syncthreads();
    for (int i = t; i < nvalid * 41; i += 512) {
        int r = i / 41, k = i - r * 41;
        u.s.A[r * KI + k] = f2bf(fedges[(size_t)row0 * 41 + i]);
    }
    __syncthreads();

    const int lane = t & 63, wid = t >> 6, l15 = lane & 15, l4 = lane >> 4;
    f32x4 acc[8];
    #pragma unroll
    for (int b = 0; b < 8; ++b) acc[b] = (f32x4){0.f, 0.f, 0.f, 0.f};

    #pragma unroll
    for (int ks = 0; ks < 2; ++ks) {
        s16x8 a = *(const s16x8*)&u.s.A[(wid * 16 + l15) * KI + ks * 32 + l4 * 8];
        #pragma unroll
        for (int c = 0; c < 8; ++c) {
            s16x8 b = *(const s16x8*)&u.s.Wi[(c * 16 + l15) * KI + ks * 32 + l4 * 8];
            acc[c] = __builtin_amdgcn_mfma_f32_16x16x32_bf16(a, b, acc[c], 0, 0, 0);
        }
    }
    __syncthreads();

    #pragma unroll
    for (int c = 0; c < 8; ++c)
        #pragma unroll
        for (int j = 0; j < 4; ++j)
            u.acc[wid * 16 + l4 * 4 + j][c * 16 + l15] = acc[c][j];
    __syncthreads();

    for (int i = t; i < Hh * 16; i += 512) {
        int row = i >> 4, seg = i & 15, grow = row0 + row;
        if (grow < Ee) {
            float4 a0 = *(const float4*)&u.acc[row][seg * 8];
            float4 a1 = *(const float4*)&u.acc[row][seg * 8 + 4];
            size_t o = (size_t)grow * Hh + seg * 8;
            uint4 bv;
            bv.x = pack2(a0.x, a0.y); bv.y = pack2(a0.z, a0.w);
            bv.z = pack2(a1.x, a1.y); bv.w = pack2(a1.z, a1.w);
            *(uint4*)&binput_bf[o] = bv;
            uint4 m;
            m.x = pack2(sigmoidf_(a0.x), sigmoidf_(a0.y));
            m.y = pack2(sigmoidf_(a0.z), sigmoidf_(a0.w));
            m.z = pack2(sigmoidf_(a1.x), sigmoidf_(a1.y));
            m.w = pack2(sigmoidf_(a1.z), sigmoidf_(a1.w));
            *(uint4*)&msg[o] = m;
        }
    }
}

// ---------------------------------------------------------------------------
// Kernel 2 (MFMA, 512 thr): msg_out = bf16(sigmoid(binput + (sum_8 msg)@W_h))
// 128 rows / block, 8 waves. LDS 73.7KB -> 2 blk/CU, 16 waves/CU.
// ---------------------------------------------------------------------------
union IterSmem {
    struct { u16 W[Hh * KP]; u16 N[Hh * KP]; } s;    // 69632 B
    float acc[Hh][ACCW];                             // 67584 B
};

__global__ __launch_bounds__(512, 4) void k_iter(
    const u16* __restrict__ msg_in, const int* __restrict__ egraph,
    const u16* __restrict__ wt_h, const u16* __restrict__ binput_bf,
    u16* __restrict__ msg_out)
{
    __shared__ IterSmem u;
    __shared__ int sEG[128 * NBn];
    const int t = threadIdx.x;
    const int row0 = blockIdx.x * 128;

    for (int i = t; i < Hh * KP / 8; i += 512)
        ((uint4*)u.s.W)[i] = ((const uint4*)wt_h)[i];
    if (t < 256) {
        int r = row0 + (t >> 1);
        int4 v = make_int4(0, 0, 0, 0);
        if (r < Ee) v = ((const int4*)egraph)[r * 2 + (t & 1)];
        ((int4*)sEG)[t] = v;
    }
    __syncthreads();

    // gather: 16 lanes/row x 16B; 32 rows per pass, 4 passes
    {
        const int s = t & 15, rl = t >> 4;
        #pragma unroll 2
        for (int pass = 0; pass < 4; ++pass) {
            int r = pass * 32 + rl;
            int grow = row0 + r;
            float a[8] = {0.f, 0.f, 0.f, 0.f, 0.f, 0.f, 0.f, 0.f};
            if (grow < Ee) {
                #pragma unroll
                for (int j = 0; j < NBn; ++j) {
                    int idx = sEG[r * NBn + j];
                    uint4 v = *(const uint4*)(msg_in + (size_t)idx * Hh + s * 8);
                    add8(a, v);
                }
            }
            uint4 o;
            o.x = pack2(a[0], a[1]); o.y = pack2(a[2], a[3]);
            o.z = pack2(a[4], a[5]); o.w = pack2(a[6], a[7]);
            *(uint4*)&u.s.N[r * KP + s * 8] = o;
        }
    }
    __syncthreads();

    const int lane = t & 63, wid = t >> 6, l15 = lane & 15, l4 = lane >> 4;
    f32x4 acc[8];
    #pragma unroll
    for (int b = 0; b < 8; ++b) acc[b] = (f32x4){0.f, 0.f, 0.f, 0.f};

    #pragma unroll
    for (int ks = 0; ks < 4; ++ks) {
        s16x8 a = *(const s16x8*)&u.s.N[(wid * 16 + l15) * KP + ks * 32 + l4 * 8];
        #pragma unroll
        for (int c = 0; c < 8; ++c) {
            s16x8 b = *(const s16x8*)&u.s.W[(c * 16 + l15) * KP + ks * 32 + l4 * 8];
            acc[c] = __builtin_amdgcn_mfma_f32_16x16x32_bf16(a, b, acc[c], 0, 0, 0);
        }
    }
    __syncthreads();

    #pragma unroll
    for (int c = 0; c < 8; ++c)
        #pragma unroll
        for (int j = 0; j < 4; ++j)
            u.acc[wid * 16 + l4 * 4 + j][c * 16 + l15] = acc[c][j];
    __syncthreads();

    for (int i = t; i < Hh * 16; i += 512) {
        int row = i >> 4, seg = i & 15, grow = row0 + row;
        if (grow < Ee) {
            float4 a0 = *(const float4*)&u.acc[row][seg * 8];
            float4 a1 = *(const float4*)&u.acc[row][seg * 8 + 4];
            size_t o = (size_t)grow * Hh + seg * 8;
            uint4 bv = *(const uint4*)&binput_bf[o];
            uint4 m;
            m.x = pack2(sigmoidf_(a0.x + bflo(bv.x)), sigmoidf_(a0.y + bfhi(bv.x)));
            m.y = pack2(sigmoidf_(a0.z + bflo(bv.y)), sigmoidf_(a0.w + bfhi(bv.y)));
            m.z = pack2(sigmoidf_(a1.x + bflo(bv.z)), sigmoidf_(a1.y + bfhi(bv.z)));
            m.w = pack2(sigmoidf_(a1.z + bflo(bv.w)), sigmoidf_(a1.w + bfhi(bv.w)));
            *(uint4*)&msg_out[o] = m;
        }
    }
}

// ---------------------------------------------------------------------------
// Kernel 3 (MFMA): hidden = bf16(sigmoid([feat|0pad|nei] @ W_o' + b_o)), K=192
// 64 rows / block, 4 waves. LDS 79.4KB -> 2 blk/CU.
// ---------------------------------------------------------------------------
union WoSmem {
    u16 Wo[Hh * KO];        // 51200 B
    float acc[64][ACCW];    // 33792 B
};

__global__ __launch_bounds__(256, 2) void k_final(
    const u16* __restrict__ msg_in, const int* __restrict__ agraph,
    const float* __restrict__ features, const u16* __restrict__ wt_o,
    const float* __restrict__ b_o, u16* __restrict__ hidden)
{
    __shared__ WoSmem uw;
    __shared__ u16 sA[64 * KO];     // 25600 B
    __shared__ int sAG[64 * NBn];   // 2048 B
    __shared__ float sBias[Hh];     // 512 B
    const int t = threadIdx.x;
    const int row0 = blockIdx.x * 64;
    const int nvalid = min(64, Nn - row0);

    for (int i = t; i < Hh * KO / 8; i += 256)
        ((uint4*)uw.Wo)[i] = ((const uint4*)wt_o)[i];
    {
        uint4 z = make_uint4(0, 0, 0, 0);
        for (int i = t; i < 64 * KO / 8; i += 256) ((uint4*)sA)[i] = z;
    }
    if (t < 128) {
        int r = row0 + (t >> 1);
        int4 v = make_int4(0, 0, 0, 0);
        if (r < Nn) v = ((const int4*)agraph)[r * 2 + (t & 1)];
        ((int4*)sAG)[t] = v;
    }
    if (t < Hh / 4) ((float4*)sBias)[t] = ((const float4*)b_o)[t];
    __syncthreads();

    for (int i = t; i < nvalid * FFn; i += 256) {
        int r = i / FFn, k = i - r * FFn;
        sA[r * KO + k] = f2bf(features[(size_t)row0 * FFn + i]);
    }
    {
        const int s = t & 15, rl = t >> 4;
        #pragma unroll 2
        for (int pass = 0; pass < 4; ++pass) {
            int r = pass * 16 + rl;
            int grow = row0 + r;
            float a[8] = {0.f, 0.f, 0.f, 0.f, 0.f, 0.f, 0.f, 0.f};
            if (grow < Nn) {
                #pragma unroll
                for (int j = 0; j < NBn; ++j) {
                    int idx = sAG[r * NBn + j];
                    uint4 v = *(const uint4*)(msg_in + (size_t)idx * Hh + s * 8);
                    add8(a, v);
                }
            }
            uint4 o;
            o.x = pack2(a[0], a[1]); o.y = pack2(a[2], a[3]);
            o.z = pack2(a[4], a[5]); o.w = pack2(a[6], a[7]);
            *(uint4*)&sA[r * KO + 64 + s * 8] = o;
        }
    }
    __syncthreads();

    const int lane = t & 63, wid = t >> 6, l15 = lane & 15, l4 = lane >> 4;
    f32x4 acc[8];
    #pragma unroll
    for (int b = 0; b < 8; ++b) acc[b] = (f32x4){0.f, 0.f, 0.f, 0.f};

    #pragma unroll
    for (int ks = 0; ks < 6; ++ks) {
        s16x8 a = *(const s16x8*)&sA[(wid * 16 + l15) * KO + ks * 32 + l4 * 8];
        #pragma unroll
        for (int c = 0; c < 8; ++c) {
            s16x8 b = *(const s16x8*)&uw.Wo[(c * 16 + l15) * KO + ks * 32 + l4 * 8];
            acc[c] = __builtin_amdgcn_mfma_f32_16x16x32_bf16(a, b, acc[c], 0, 0, 0);
        }
    }
    __syncthreads();

    #pragma unroll
    for (int c = 0; c < 8; ++c)
        #pragma unroll
        for (int j = 0; j < 4; ++j)
            uw.acc[wid * 16 + l4 * 4 + j][c * 16 + l15] = acc[c][j];
    __syncthreads();

    for (int i = t; i < 64 * 16; i += 256) {
        int row = i >> 4, seg = i & 15, grow = row0 + row;
        if (grow < Nn) {
            float4 a0 = *(const float4*)&uw.acc[row][seg * 8];
            float4 a1 = *(const float4*)&uw.acc[row][seg * 8 + 4];
            const float* bb = &sBias[seg * 8];
            uint4 m;
            m.x = pack2(sigmoidf_(a0.x + bb[0]), sigmoidf_(a0.y + bb[1]));
            m.y = pack2(sigmoidf_(a0.z + bb[2]), sigmoidf_(a0.w + bb[3]));
            m.z = pack2(sigmoidf_(a1.x + bb[4]), sigmoidf_(a1.y + bb[5]));
            m.w = pack2(sigmoidf_(a1.z + bb[6]), sigmoidf_(a1.w + bb[7]));
            *(uint4*)&hidden[(size_t)grow * Hh + seg * 8] = m;
        }
    }
}

// ---------------------------------------------------------------------------
// Kernel 4: segment mean over bf16 hidden. One block (128 threads) / molecule.
// ---------------------------------------------------------------------------
__global__ __launch_bounds__(128) void k_pool(
    const u16* __restrict__ hidden, const int* __restrict__ scope,
    float* __restrict__ out)
{
    const int b = blockIdx.x;
    const int t = threadIdx.x;
    const int start = scope[b * 2 + 0];
    const int len   = scope[b * 2 + 1];
    float acc = 0.f;
    for (int i = 0; i < len; ++i)
        acc += bf1(hidden[(size_t)(start + i) * Hh + t]);
    out[(size_t)b * Hh + t] = acc / (float)len;
}

// ---------------------------------------------------------------------------
extern "C" void kernel_launch(void* const* d_in, const int* in_sizes, int n_in,
                              void* d_out, int out_size, void* d_ws, size_t ws_size,
                              hipStream_t stream)
{
    const float* features = (const float*)d_in[0];
    const float* fedges   = (const float*)d_in[1];
    const int*   agraph   = (const int*)d_in[2];
    const int*   egraph   = (const int*)d_in[3];
    const int*   scope    = (const int*)d_in[4];
    const float* W_i      = (const float*)d_in[5];
    const float* W_h      = (const float*)d_in[6];
    const float* W_o      = (const float*)d_in[7];
    const float* b_o      = (const float*)d_in[8];
    float* out = (float*)d_out;

    // Workspace: binput bf16[E*128] | msg0 bf16[E*128] | msg1 bf16[E*128] | wt_h
    // wt_i parks in msg1 (dead until iter0 writes it); wt_o parks in binput
    // (dead after iter5) and is prepped just before k_final.
    u16* binput_bf = (u16*)d_ws;
    u16* msg0 = binput_bf + (size_t)Ee * Hh;
    u16* msg1 = msg0 + (size_t)Ee * Hh;
    u16* wt_h = msg1 + (size_t)Ee * Hh;
    u16* wt_i = msg1;               // 18432 B, consumed by k_binput only
    u16* wt_o = binput_bf;          // 51200 B, consumed by k_final only

    k_prep1<<<(Hh * KP + Hh * KI) / 256, 256, 0, stream>>>(W_h, W_i, wt_h, wt_i);

    const int eblocks = (Ee + 127) / 128;
    k_binput<<<eblocks, 512, 0, stream>>>(fedges, wt_i, binput_bf, msg0);

    u16* src = msg0;
    u16* dst = msg1;
    for (int d = 0; d < ITERS; ++d) {
        k_iter<<<eblocks, 512, 0, stream>>>(src, egraph, wt_h, binput_bf, dst);
        u16* tmp = src; src = dst; dst = tmp;
    }
    // final message in `src` (= msg1); binput now dead -> prep wt_o there.
    k_prep2<<<(Hh * KO) / 256, 256, 0, stream>>>(W_o, wt_o);

    u16* hidden = dst;   // = msg0 region
    const int nblocks = (Nn + 63) / 64;
    k_final<<<nblocks, 256, 0, stream>>>(src, agraph, features, wt_o, b_o, hidden);

    k_pool<<<Bm, 128, 0, stream>>>(hidden, scope, out);
}